// Round 1
// baseline (1042.181 us; speedup 1.0000x reference)
//
#include <hip/hip_runtime.h>
#include <math.h>

#define Bz 64
#define Tz 32
#define Ez 64
#define Hz 256
#define Vz 32000
#define NBLK_L 250     // 32000 / 128 cols per logits block
#define PSTRIDE 256    // partial-argmax stride per row

// ---------------- weight repack: P[j][k][g], k in [0,320), g in {i,f,o,c} ----------------
__global__ void k_prep(const float* __restrict__ Wi, const float* __restrict__ Ui,
                       const float* __restrict__ Wf, const float* __restrict__ Uf,
                       const float* __restrict__ Wog, const float* __restrict__ Uog,
                       const float* __restrict__ Wc, const float* __restrict__ Uc,
                       float* __restrict__ P) {
  int j = blockIdx.x;        // 0..255
  int k = threadIdx.x;       // 0..319
  float gi, gf, go, gc;
  if (k < Ez) {
    gi = Wi[k*Hz + j]; gf = Wf[k*Hz + j]; go = Wog[k*Hz + j]; gc = Wc[k*Hz + j];
  } else {
    int kk = k - Ez;
    gi = Ui[kk*Hz + j]; gf = Uf[kk*Hz + j]; go = Uog[kk*Hz + j]; gc = Uc[kk*Hz + j];
  }
  float* p = P + ((size_t)j*320 + k)*4;
  p[0] = gi; p[1] = gf; p[2] = go; p[3] = gc;
}

// ---------------- per-step LSTM cell (token pick + gather + 4-gate matmul + state) -------
// grid 64 blocks (j-tile of 4), 256 threads: thread = (b = tid>>2, jl = tid&3)
__global__ __launch_bounds__(256) void k_gates(
    int t,
    const int* __restrict__ gnp,
    const int* __restrict__ input_x,
    const int* __restrict__ start_tok,
    const float* __restrict__ emb,
    const float* __restrict__ P,
    const float* __restrict__ bi_, const float* __restrict__ bf_,
    const float* __restrict__ bog_, const float* __restrict__ bc_,
    float* __restrict__ h_g, float* __restrict__ c_g,
    const float* __restrict__ pv, const int* __restrict__ pi,
    int* __restrict__ out) {
  extern __shared__ float smem[];
  float* w_lds   = smem;                       // 4*1284 = 5136 floats (1280 used + 4 pad per j)
  float* x_lds   = smem + 5136;                // 64*68 = 4352 floats (stride 68 vs bank stride)
  int*   tok_lds = (int*)(smem + 5136 + 4352); // 64
  float* redv    = smem + 5136 + 4352 + 64;    // 256
  int*   redi    = (int*)(smem + 5136 + 4352 + 64 + 256); // 256

  int tid = threadIdx.x;
  int jb  = blockIdx.x;      // 0..63
  int gn  = *gnp;
  int b   = tid >> 2, q = tid & 3;

  // ---- pre-phase: decide previous token (redundant per block; block 0 writes out) ----
  if (t == 0) {
    if (q == 0) tok_lds[b] = start_tok[b];
  } else if (t - 1 < gn) {
    if (q == 0) {
      int tk = input_x[b*Tz + (t-1)];
      tok_lds[b] = tk;
      if (jb == 0) out[b*Tz + (t-1)] = tk;
    }
  } else {
    float bv = -3.4e38f; int bix = 0x7fffffff;
    for (int i = q; i < NBLK_L; i += 4) {
      float v = pv[b*PSTRIDE + i]; int id = pi[b*PSTRIDE + i];
      if (v > bv || (v == bv && id < bix)) { bv = v; bix = id; }
    }
    redv[b*4+q] = bv; redi[b*4+q] = bix;
    __syncthreads();
    if (q == 0) {
      for (int i = 1; i < 4; ++i) {
        float v = redv[b*4+i]; int id = redi[b*4+i];
        if (v > bv || (v == bv && id < bix)) { bv = v; bix = id; }
      }
      tok_lds[b] = bix;
      if (jb == 0) out[b*Tz + (t-1)] = bix;
    }
  }
  __syncthreads();

  // ---- stage x = emb[tok] and this block's packed weight tile ----
  const float4* emb4 = (const float4*)emb;
  for (int idx = tid; idx < Bz*16; idx += 256) {
    int b2 = idx >> 4, e4 = idx & 15;
    float4 v = emb4[(size_t)tok_lds[b2]*16 + e4];
    float* dst = x_lds + b2*68 + e4*4;
    dst[0]=v.x; dst[1]=v.y; dst[2]=v.z; dst[3]=v.w;
  }
  int j0 = jb*4;
  for (int idx = tid; idx < 4*1280; idx += 256) {
    int jj = idx / 1280, rem = idx - jj*1280;
    w_lds[jj*1284 + rem] = P[(size_t)(j0+jj)*1280 + rem];
  }
  __syncthreads();

  // ---- main dot: 4 gates for (b, j) ----
  int jl = tid & 3;
  const float* arow = x_lds + b*68;
  const float* wrow = w_lds + jl*1284;
  float ai=0.f, af=0.f, ao=0.f, ac=0.f;
  #pragma unroll
  for (int k0 = 0; k0 < Ez; k0 += 4) {
    float4 av = *(const float4*)(arow + k0);
    const float* ap = (const float*)&av;
    #pragma unroll
    for (int kk = 0; kk < 4; ++kk) {
      float4 wv = *(const float4*)(wrow + (k0+kk)*4);
      float a = ap[kk];
      ai = fmaf(a, wv.x, ai); af = fmaf(a, wv.y, af);
      ao = fmaf(a, wv.z, ao); ac = fmaf(a, wv.w, ac);
    }
  }
  if (t > 0) {
    const float4* hrow = (const float4*)(h_g + b*Hz);
    #pragma unroll 4
    for (int k0 = 0; k0 < Hz; k0 += 4) {
      float4 av = hrow[k0 >> 2];
      const float* ap = (const float*)&av;
      #pragma unroll
      for (int kk = 0; kk < 4; ++kk) {
        float4 wv = *(const float4*)(wrow + (Ez+k0+kk)*4);
        float a = ap[kk];
        ai = fmaf(a, wv.x, ai); af = fmaf(a, wv.y, af);
        ao = fmaf(a, wv.z, ao); ac = fmaf(a, wv.w, ac);
      }
    }
  }
  int j = j0 + jl;
  float gi = 1.f/(1.f + expf(-(ai + bi_[j])));
  float gf = 1.f/(1.f + expf(-(af + bf_[j])));
  float go = 1.f/(1.f + expf(-(ao + bog_[j])));
  float gc = tanhf(ac + bc_[j]);
  float cold = (t > 0) ? c_g[b*Hz + j] : 0.f;
  float cn = gf*cold + gi*gc;
  float hn = go * tanhf(cn);
  c_g[b*Hz + j] = cn;
  h_g[b*Hz + j] = hn;
}

// ---------------- logits + fused per-row partial argmax ---------------------------------
// grid 250 blocks (128 cols each), 512 threads: thread = (rg = tid>>5 -> 4 rows, cg -> 4 cols)
__global__ __launch_bounds__(512) void k_logits(
    int t, const int* __restrict__ gnp,
    const float* __restrict__ h_g,
    const float* __restrict__ Wo, const float* __restrict__ bo,
    float* __restrict__ pv, int* __restrict__ pi) {
  int gn = *gnp;
  if (t < gn) return;     // teacher step: no sampling needed
  extern __shared__ float h_lds[];   // 64*256 floats = 64KB
  int tid = threadIdx.x;
  const float4* hg4 = (const float4*)h_g;
  float4* hl4 = (float4*)h_lds;
  for (int idx = tid; idx < Bz*Hz/4; idx += 512) hl4[idx] = hg4[idx];
  __syncthreads();

  int rg = tid >> 5, cg = tid & 31;
  int r0 = rg*4;
  int cbase = blockIdx.x * 128;
  int c0 = cbase + cg*4;
  float4 bo4 = *(const float4*)(bo + c0);
  float acc[4][4];
  #pragma unroll
  for (int i = 0; i < 4; ++i) { acc[i][0]=bo4.x; acc[i][1]=bo4.y; acc[i][2]=bo4.z; acc[i][3]=bo4.w; }

  const float4* Wo4 = (const float4*)Wo;
  int cq = c0 >> 2;
  for (int k = 0; k < Hz; k += 4) {
    float4 H0 = *(const float4*)(h_lds + (r0+0)*Hz + k);
    float4 H1 = *(const float4*)(h_lds + (r0+1)*Hz + k);
    float4 H2 = *(const float4*)(h_lds + (r0+2)*Hz + k);
    float4 H3 = *(const float4*)(h_lds + (r0+3)*Hz + k);
    const float* hp0 = (const float*)&H0;
    const float* hp1 = (const float*)&H1;
    const float* hp2 = (const float*)&H2;
    const float* hp3 = (const float*)&H3;
    #pragma unroll
    for (int kk = 0; kk < 4; ++kk) {
      float4 w = Wo4[(size_t)(k+kk)*8000 + cq];
      const float* wp = (const float*)&w;
      float a0 = hp0[kk], a1 = hp1[kk], a2 = hp2[kk], a3 = hp3[kk];
      #pragma unroll
      for (int cc = 0; cc < 4; ++cc) {
        acc[0][cc] = fmaf(a0, wp[cc], acc[0][cc]);
        acc[1][cc] = fmaf(a1, wp[cc], acc[1][cc]);
        acc[2][cc] = fmaf(a2, wp[cc], acc[2][cc]);
        acc[3][cc] = fmaf(a3, wp[cc], acc[3][cc]);
      }
    }
  }

  // per-row argmax over this block's 128 cols (first-index-wins tie break)
  #pragma unroll
  for (int i = 0; i < 4; ++i) {
    float bv = acc[i][0]; int bix = c0;
    #pragma unroll
    for (int cc = 1; cc < 4; ++cc)
      if (acc[i][cc] > bv) { bv = acc[i][cc]; bix = c0 + cc; }
    for (int m = 16; m > 0; m >>= 1) {
      float ov = __shfl_xor(bv, m, 32);
      int   oi = __shfl_xor(bix, m, 32);
      if (ov > bv || (ov == bv && oi < bix)) { bv = ov; bix = oi; }
    }
    if (cg == 0) {
      pv[(r0+i)*PSTRIDE + blockIdx.x] = bv;
      pi[(r0+i)*PSTRIDE + blockIdx.x] = bix;
    }
  }
}

// ---------------- final token (step T-1) -------------------------------------------------
__global__ void k_final(const int* __restrict__ gnp, const int* __restrict__ input_x,
                        const float* __restrict__ pv, const int* __restrict__ pi,
                        int* __restrict__ out) {
  int b = threadIdx.x;
  int gn = *gnp;
  int tk;
  if (Tz - 1 < gn) {
    tk = input_x[b*Tz + Tz-1];
  } else {
    float bv = -3.4e38f; int bix = 0x7fffffff;
    for (int i = 0; i < NBLK_L; ++i) {
      float v = pv[b*PSTRIDE + i]; int id = pi[b*PSTRIDE + i];
      if (v > bv || (v == bv && id < bix)) { bv = v; bix = id; }
    }
    tk = bix;
  }
  out[b*Tz + Tz-1] = tk;
}

extern "C" void kernel_launch(void* const* d_in, const int* in_sizes, int n_in,
                              void* d_out, int out_size, void* d_ws, size_t ws_size,
                              hipStream_t stream) {
  const int*   input_x   = (const int*)d_in[0];
  const int*   gnp       = (const int*)d_in[1];
  const int*   start_tok = (const int*)d_in[2];
  const float* emb = (const float*)d_in[3];
  const float* Wi  = (const float*)d_in[4];
  const float* Ui  = (const float*)d_in[5];
  const float* bi  = (const float*)d_in[6];
  const float* Wf  = (const float*)d_in[7];
  const float* Uf  = (const float*)d_in[8];
  const float* bff = (const float*)d_in[9];
  const float* Wog = (const float*)d_in[10];
  const float* Uog = (const float*)d_in[11];
  const float* bog = (const float*)d_in[12];
  const float* Wc  = (const float*)d_in[13];
  const float* Uc  = (const float*)d_in[14];
  const float* bc  = (const float*)d_in[15];
  const float* Wo  = (const float*)d_in[16];
  const float* bo  = (const float*)d_in[17];
  int* out = (int*)d_out;

  float* wsf = (float*)d_ws;
  float* h_g = wsf;                    // 16384 f
  float* c_g = wsf + 16384;            // 16384 f
  float* pv  = wsf + 32768;            // 16384 f
  int*   pi  = (int*)(wsf + 49152);    // 16384 i
  float* P   = wsf + 65536;            // 327680 f packed gate weights

  k_prep<<<dim3(256), dim3(320), 0, stream>>>(Wi, Ui, Wf, Uf, Wog, Uog, Wc, Uc, P);

  size_t gsm = (size_t)(5136 + 4352 + 64 + 256 + 256) * 4;  // 40256 B
  for (int t = 0; t < Tz; ++t) {
    k_gates<<<dim3(64), dim3(256), gsm, stream>>>(
        t, gnp, input_x, start_tok, emb, P, bi, bff, bog, bc, h_g, c_g, pv, pi, out);
    k_logits<<<dim3(NBLK_L), dim3(512), 65536, stream>>>(
        t, gnp, h_g, Wo, bo, pv, pi);
  }
  k_final<<<dim3(1), dim3(64), 0, stream>>>(gnp, input_x, pv, pi, out);
}